// Round 3
// baseline (389.438 us; speedup 1.0000x reference)
//
#include <hip/hip_runtime.h>

// Problem constants
#define B_  16
#define T_  12
#define N_  1000
#define F_  64
#define KC  3
#define O_  64
#define NP  1024            // padded N (both i and j dims)
#define KP  (KC * NP)       // 3072 combined contraction length per b
#define CC  (T_ * O_)       // 768 output columns per b

typedef __bf16 bf16x8 __attribute__((ext_vector_type(8)));
typedef float  f32x4  __attribute__((ext_vector_type(4)));

__device__ __forceinline__ unsigned short f2bf(float f) {
  __bf16 h = (__bf16)f;                      // RNE convert
  return __builtin_bit_cast(unsigned short, h);
}

// async global->LDS, 16B per lane. LDS dest = wave-uniform base + lane*16.
__device__ __forceinline__ void gl_lds16(const void* g, void* l) {
  __builtin_amdgcn_global_load_lds(
      (const __attribute__((address_space(1))) unsigned int*)g,
      (__attribute__((address_space(3))) unsigned int*)l,
      16, 0, 0);
}

// ---------------------------------------------------------------------------
// Stage 1: ASt[b][ip][k][jp] = bf16(cheb[k,j,i] * SAtt[b,j,i]), zero-padded.
// 64x64 (j x i) tile, transpose via LDS. float4 loads, uint4 stores.
// grid (i-tile, j-tile, b) = (16,16,16)   [unchanged from round 2]
// ---------------------------------------------------------------------------
__global__ __launch_bounds__(256) void k_build_as(
    const float* __restrict__ SAtt, const float* __restrict__ cheb,
    unsigned short* __restrict__ ASt) {
  __shared__ unsigned short prod[KC][64][66];
  const int tid = threadIdx.x;
  const int b = blockIdx.z, ib = blockIdx.x * 64, jb = blockIdx.y * 64;

  const int ii4 = (tid & 15) * 4, jr = tid >> 4;
#pragma unroll
  for (int p = 0; p < 4; ++p) {
    const int jj = p * 16 + jr;
    const int gj = jb + jj;
    const int gjc = gj < N_ ? gj : N_ - 1;
    const int gi = ib + ii4;                    // N_%4==0: f4 never straddles
    const bool iok = gi < N_;
    const bool ok = iok && (gj < N_);
    float4 s4 = make_float4(0.f, 0.f, 0.f, 0.f);
    if (iok) s4 = *(const float4*)&SAtt[((size_t)b * N_ + gjc) * N_ + gi];
#pragma unroll
    for (int k = 0; k < KC; ++k) {
      float4 c4 = make_float4(0.f, 0.f, 0.f, 0.f);
      if (iok) c4 = *(const float4*)&cheb[((size_t)k * N_ + gjc) * N_ + gi];
      ushort2 lo, hi;
      lo.x = ok ? f2bf(c4.x * s4.x) : (unsigned short)0;
      lo.y = ok ? f2bf(c4.y * s4.y) : (unsigned short)0;
      hi.x = ok ? f2bf(c4.z * s4.z) : (unsigned short)0;
      hi.y = ok ? f2bf(c4.w * s4.w) : (unsigned short)0;
      *(ushort2*)&prod[k][jj][ii4]     = lo;
      *(ushort2*)&prod[k][jj][ii4 + 2] = hi;
    }
  }
  __syncthreads();

  const int j8 = (tid & 7) * 8, i0 = tid >> 3;
#pragma unroll
  for (int p = 0; p < 2; ++p) {
    const int iw = p * 32 + i0;
#pragma unroll
    for (int k = 0; k < KC; ++k) {
      unsigned short v[8];
#pragma unroll
      for (int m = 0; m < 8; ++m) v[m] = prod[k][j8 + m][iw];
      *(uint4*)&ASt[((size_t)(b * NP + ib + iw) * KC + k) * NP + jb + j8] =
          *(uint4*)v;
    }
  }
}

// ---------------------------------------------------------------------------
// Stage 2: Yt[b][t][o][k][jp] = bf16(sum_f x[b,t,j,f] * Theta[k,f,o]).
// 64-j blocks: LDS 45 KB -> 3 blocks/CU (was 2), grid (16, 192) = 3072 blocks.
// MFMA A = Theta^T (M=o=64), B = x strip (N=j=16/wave), K=f=64.
// ---------------------------------------------------------------------------
__global__ __launch_bounds__(256) void k_build_y(
    const float* __restrict__ x, const float* __restrict__ Theta,
    unsigned short* __restrict__ Yt) {
  __shared__ unsigned short thl[KC][64][72];  // Theta^T [k][o][f], 27.0 KB
  __shared__ unsigned short xl[64][72];       // x tile [j][f], 9.0 KB
  __shared__ unsigned short ot[64][72];       // out tile [o][j], 9.0 KB
  const int tid = threadIdx.x;
  const int bt = blockIdx.y;                  // b*T + t
  const int jb = blockIdx.x * 64;

  // Theta -> thl (transposed): float4 loads
#pragma unroll
  for (int it = 0; it < 12; ++it) {
    const int e = (tid + it * 256) * 4;
    const int k = e >> 12, f = (e >> 6) & 63, o0 = e & 63;
    const float4 v = *(const float4*)&Theta[e];
    thl[k][o0 + 0][f] = f2bf(v.x);
    thl[k][o0 + 1][f] = f2bf(v.y);
    thl[k][o0 + 2][f] = f2bf(v.z);
    thl[k][o0 + 3][f] = f2bf(v.w);
  }
  // x chunk (64 j-rows x 64 f) -> xl as bf16, float4 loads
  const float* xrow = x + ((size_t)bt * N_ + jb) * F_;
#pragma unroll
  for (int p = 0; p < 4; ++p) {
    const int i4 = tid + p * 256;            // float4 index, 0..1023
    const int fl = i4 * 4, j = fl >> 6, f = fl & 63;
    float4 v;
    if (jb + j < N_) v = ((const float4*)xrow)[i4];
    else             v = make_float4(0.f, 0.f, 0.f, 0.f);
    ushort4 u;
    u.x = f2bf(v.x); u.y = f2bf(v.y); u.z = f2bf(v.z); u.w = f2bf(v.w);
    *(ushort4*)&xl[j][f] = u;
  }
  __syncthreads();

  const int w = tid >> 6, l = tid & 63, quad = l >> 4, lr = l & 15;
  const int os = tid >> 2, q = tid & 3;       // store phase indices
#pragma unroll
  for (int k = 0; k < KC; ++k) {
    f32x4 acc[4];
#pragma unroll
    for (int mi = 0; mi < 4; ++mi) acc[mi] = (f32x4){0.f, 0.f, 0.f, 0.f};
#pragma unroll
    for (int ks = 0; ks < 2; ++ks) {
      const int fo = ks * 32 + quad * 8;
      const bf16x8 bb = *(const bf16x8*)&xl[w * 16 + lr][fo];
#pragma unroll
      for (int mi = 0; mi < 4; ++mi) {
        const bf16x8 a = *(const bf16x8*)&thl[k][mi * 16 + lr][fo];
        acc[mi] = __builtin_amdgcn_mfma_f32_16x16x32_bf16(a, bb, acc[mi], 0, 0, 0);
      }
    }
    __syncthreads();                          // protect ot from prior readers
#pragma unroll
    for (int mi = 0; mi < 4; ++mi)
#pragma unroll
      for (int r = 0; r < 4; ++r)
        ot[mi * 16 + quad * 4 + r][w * 16 + lr] = f2bf(acc[mi][r]);
    __syncthreads();
    // coalesced stores: 4 lanes x 16B = 64B contiguous per o-row, 2 per thread
    unsigned short* yrow = &Yt[((size_t)(bt * O_ + os) * KC + k) * NP + jb];
    *(uint4*)&yrow[q * 8]      = *(const uint4*)&ot[os][q * 8];
    *(uint4*)&yrow[32 + q * 8] = *(const uint4*)&ot[os][32 + q * 8];
  }
}

// ---------------------------------------------------------------------------
// Stage 3: per-b GEMM  C[i,c] = sum_{K'} ASt[b][i][K'] * Yt[b][c][K'].
// A via LDS (global_load_lds + XOR swizzle); B DIRECT TO VGPR from Yt
// (16 rows x 64B fully-consumed lines per wave) -- halves LDS traffic and
// staging. 128x128 tile, 4 waves x 64x64, 16x16x32 bf16 MFMA, BK=64.
// ---------------------------------------------------------------------------
__global__ __launch_bounds__(256, 3) void k_gemm(
    const unsigned short* __restrict__ ASt, const unsigned short* __restrict__ Yt,
    float* __restrict__ out) {
  __shared__ unsigned short Al[128 * 64];   // 16 KB
  const int tid = threadIdx.x;
  // block swizzle: bid%8 -> XCD; 2 b's per XCD for L2 locality
  const int bid = blockIdx.x;
  const int xcd = bid & 7, s = bid >> 3;          // s = 0..95
  const int b = xcd * 2 + (s / 48);
  const int r48 = s % 48;
  const int ib = (r48 / 6) * 128, cb = (r48 % 6) * 128;

  const unsigned short* Abase = ASt + ((size_t)b * NP + ib) * KP;
  const int w = tid >> 6, l = tid & 63, quad = l >> 4, lr = l & 15;
  const int wr = w & 1, wc = w >> 1;
  const int lrow = l >> 3, lchunk = l & 7;
  const int src_chunk = lchunk ^ lrow;            // XOR swizzle (staging side)
  const int p0 = quad ^ (lr & 7);                 // phys chunk, ks=0 (read side)

  // B-operand row base for this lane: c = cb + wc*64 + ci*16 + lr
  const unsigned short* Br0 =
      Yt + ((size_t)(b * CC + cb + wc * 64 + lr)) * KP + quad * 8;

  f32x4 acc[4][4];
#pragma unroll
  for (int mi = 0; mi < 4; ++mi)
#pragma unroll
    for (int ci = 0; ci < 4; ++ci)
      acc[mi][ci] = (f32x4){0.f, 0.f, 0.f, 0.f};

  for (int kt = 0; kt < KP / 64; ++kt) {
    __syncthreads();                        // all waves done reading Al(kt-1)
    const int k0 = kt * 64;
    // A staging (async -> LDS) and B loads (-> VGPR) share one latency window
#pragma unroll
    for (int s4 = 0; s4 < 4; ++s4) {
      const int row = w * 32 + s4 * 8;
      gl_lds16(Abase + (size_t)(row + lrow) * KP + k0 + src_chunk * 8,
               &Al[row * 64]);
    }
    bf16x8 bf[2][4];
#pragma unroll
    for (int ks = 0; ks < 2; ++ks)
#pragma unroll
      for (int ci = 0; ci < 4; ++ci)
        bf[ks][ci] =
            *(const bf16x8*)&Br0[(size_t)ci * 16 * KP + k0 + ks * 32];
    __syncthreads();                        // vmcnt(0): Al + bf all ready
#pragma unroll
    for (int ks = 0; ks < 2; ++ks) {
      const int pc = (p0 ^ (ks * 4)) * 8;   // swizzled chunk -> ushort offset
      bf16x8 a[4];
#pragma unroll
      for (int mi = 0; mi < 4; ++mi)
        a[mi] = *(const bf16x8*)&Al[(wr * 64 + mi * 16 + lr) * 64 + pc];
#pragma unroll
      for (int mi = 0; mi < 4; ++mi)
#pragma unroll
        for (int ci = 0; ci < 4; ++ci)
          acc[mi][ci] = __builtin_amdgcn_mfma_f32_16x16x32_bf16(
              a[mi], bf[ks][ci], acc[mi][ci], 0, 0, 0);
    }
  }

  // epilogue: C/D layout col=lane&15 (->c), row=quad*4+reg (->i). ReLU fused.
#pragma unroll
  for (int mi = 0; mi < 4; ++mi) {
    const int i = ib + wr * 64 + mi * 16 + quad * 4;
#pragma unroll
    for (int ci = 0; ci < 4; ++ci) {
      const int c = cb + wc * 64 + ci * 16 + lr;
      const int t = c >> 6, o = c & 63;      // 16-aligned tile: single t
#pragma unroll
      for (int r = 0; r < 4; ++r) {
        if (i + r < N_) {
          const float v = acc[mi][ci][r];
          out[((size_t)(b * T_ + t) * N_ + (i + r)) * O_ + o] = v > 0.f ? v : 0.f;
        }
      }
    }
  }
}

// ---------------------------------------------------------------------------
extern "C" void kernel_launch(void* const* d_in, const int* in_sizes, int n_in,
                              void* d_out, int out_size, void* d_ws, size_t ws_size,
                              hipStream_t stream) {
  const float* x     = (const float*)d_in[0];
  const float* SAtt  = (const float*)d_in[1];
  const float* cheb  = (const float*)d_in[2];
  const float* Theta = (const float*)d_in[3];
  float* out = (float*)d_out;

  unsigned short* ASt = (unsigned short*)d_ws;                 // 100.7 MB
  unsigned short* Yt  = ASt + (size_t)B_ * NP * KC * NP;       //  75.5 MB

  k_build_as<<<dim3(16, 16, B_), 256, 0, stream>>>(SAtt, cheb, ASt);
  k_build_y<<<dim3(16, B_ * T_), 256, 0, stream>>>(x, Theta, Yt);
  k_gemm<<<768, 256, 0, stream>>>(ASt, Yt, out);
}

// Round 4
// 342.551 us; speedup vs baseline: 1.1369x; 1.1369x over previous
//
#include <hip/hip_runtime.h>

// Problem constants
#define B_  16
#define T_  12
#define N_  1000
#define F_  64
#define KC  3
#define O_  64
#define NP  1024            // padded N (both i and j dims)
#define KP  (KC * NP)       // 3072 combined contraction length per b
#define CC  (T_ * O_)       // 768 output columns per b

typedef __bf16 bf16x8 __attribute__((ext_vector_type(8)));
typedef float  f32x4  __attribute__((ext_vector_type(4)));

__device__ __forceinline__ unsigned short f2bf(float f) {
  __bf16 h = (__bf16)f;                      // RNE convert
  return __builtin_bit_cast(unsigned short, h);
}

// async global->LDS, 16B per lane. LDS dest = wave-uniform base + lane*16.
__device__ __forceinline__ void gl_lds16(const void* g, void* l) {
  __builtin_amdgcn_global_load_lds(
      (const __attribute__((address_space(1))) unsigned int*)g,
      (__attribute__((address_space(3))) unsigned int*)l,
      16, 0, 0);
}

// ---------------------------------------------------------------------------
// Prep (fused stage1 + stage2, one launch):
//  blocks [0,4096):  ASt[b][ip][k][jp] = bf16(cheb[k,j,i]*SAtt[b,j,i]) (0-pad)
//  blocks [4096,7168): Yt[b][t][o][k][jp] = bf16(sum_f x[b,t,j,f]*Theta[k,f,o])
// ---------------------------------------------------------------------------
__global__ __launch_bounds__(256) void k_prep(
    const float* __restrict__ x, const float* __restrict__ SAtt,
    const float* __restrict__ cheb, const float* __restrict__ Theta,
    unsigned short* __restrict__ ASt, unsigned short* __restrict__ Yt) {
  __shared__ union {
    struct { unsigned short prod[KC][64][66]; } s1;                 // 25.9 KB
    struct {
      unsigned short thl[KC][64][72];   // Theta^T [k][o][f]
      unsigned short xl[64][72];        // x tile [j][f]
      unsigned short ot[64][72];        // out tile [o][j]
    } s2;                                                            // 45 KB
  } sm;
  const int tid = threadIdx.x;
  const int bid = blockIdx.x;

  if (bid < 4096) {
    // ---- stage 1: 64x64 (j x i) transpose tile -------------------------
    const int ib = (bid & 15) * 64, jb = ((bid >> 4) & 15) * 64, b = bid >> 8;
    const int ii4 = (tid & 15) * 4, jr = tid >> 4;
#pragma unroll
    for (int p = 0; p < 4; ++p) {
      const int jj = p * 16 + jr;
      const int gj = jb + jj;
      const int gjc = gj < N_ ? gj : N_ - 1;
      const int gi = ib + ii4;                  // N_%4==0: f4 never straddles
      const bool iok = gi < N_;
      const bool ok = iok && (gj < N_);
      float4 s4 = make_float4(0.f, 0.f, 0.f, 0.f);
      if (iok) s4 = *(const float4*)&SAtt[((size_t)b * N_ + gjc) * N_ + gi];
#pragma unroll
      for (int k = 0; k < KC; ++k) {
        float4 c4 = make_float4(0.f, 0.f, 0.f, 0.f);
        if (iok) c4 = *(const float4*)&cheb[((size_t)k * N_ + gjc) * N_ + gi];
        ushort2 lo, hi;
        lo.x = ok ? f2bf(c4.x * s4.x) : (unsigned short)0;
        lo.y = ok ? f2bf(c4.y * s4.y) : (unsigned short)0;
        hi.x = ok ? f2bf(c4.z * s4.z) : (unsigned short)0;
        hi.y = ok ? f2bf(c4.w * s4.w) : (unsigned short)0;
        *(ushort2*)&sm.s1.prod[k][jj][ii4]     = lo;
        *(ushort2*)&sm.s1.prod[k][jj][ii4 + 2] = hi;
      }
    }
    __syncthreads();
    const int j8 = (tid & 7) * 8, i0 = tid >> 3;
#pragma unroll
    for (int p = 0; p < 2; ++p) {
      const int iw = p * 32 + i0;
#pragma unroll
      for (int k = 0; k < KC; ++k) {
        unsigned short v[8];
#pragma unroll
        for (int m = 0; m < 8; ++m) v[m] = sm.s1.prod[k][j8 + m][iw];
        *(uint4*)&ASt[((size_t)(b * NP + ib + iw) * KC + k) * NP + jb + j8] =
            *(uint4*)v;
      }
    }
  } else {
    // ---- stage 2: MFMA A=Theta^T (M=o=64), B=x strip, K=f=64 ----------
    const int b2 = bid - 4096;
    const int jb = (b2 & 15) * 64, bt = b2 >> 4;   // bt = b*T + t
#pragma unroll
    for (int it = 0; it < 12; ++it) {
      const int e = (tid + it * 256) * 4;
      const int k = e >> 12, f = (e >> 6) & 63, o0 = e & 63;
      const float4 v = *(const float4*)&Theta[e];
      sm.s2.thl[k][o0 + 0][f] = f2bf(v.x);
      sm.s2.thl[k][o0 + 1][f] = f2bf(v.y);
      sm.s2.thl[k][o0 + 2][f] = f2bf(v.z);
      sm.s2.thl[k][o0 + 3][f] = f2bf(v.w);
    }
    const float* xrow = x + ((size_t)bt * N_ + jb) * F_;
#pragma unroll
    for (int p = 0; p < 4; ++p) {
      const int i4 = tid + p * 256;            // float4 index, 0..1023
      const int fl = i4 * 4, j = fl >> 6, f = fl & 63;
      float4 v;
      if (jb + j < N_) v = ((const float4*)xrow)[i4];
      else             v = make_float4(0.f, 0.f, 0.f, 0.f);
      ushort4 u;
      u.x = f2bf(v.x); u.y = f2bf(v.y); u.z = f2bf(v.z); u.w = f2bf(v.w);
      *(ushort4*)&sm.s2.xl[j][f] = u;
    }
    __syncthreads();

    const int w = tid >> 6, l = tid & 63, quad = l >> 4, lr = l & 15;
    const int os = tid >> 2, q = tid & 3;
#pragma unroll
    for (int k = 0; k < KC; ++k) {
      f32x4 acc[4];
#pragma unroll
      for (int mi = 0; mi < 4; ++mi) acc[mi] = (f32x4){0.f, 0.f, 0.f, 0.f};
#pragma unroll
      for (int ks = 0; ks < 2; ++ks) {
        const int fo = ks * 32 + quad * 8;
        const bf16x8 bb = *(const bf16x8*)&sm.s2.xl[w * 16 + lr][fo];
#pragma unroll
        for (int mi = 0; mi < 4; ++mi) {
          const bf16x8 a = *(const bf16x8*)&sm.s2.thl[k][mi * 16 + lr][fo];
          acc[mi] =
              __builtin_amdgcn_mfma_f32_16x16x32_bf16(a, bb, acc[mi], 0, 0, 0);
        }
      }
      __syncthreads();                          // protect ot from prior readers
#pragma unroll
      for (int mi = 0; mi < 4; ++mi)
#pragma unroll
        for (int r = 0; r < 4; ++r)
          sm.s2.ot[mi * 16 + quad * 4 + r][w * 16 + lr] = f2bf(acc[mi][r]);
      __syncthreads();
      unsigned short* yrow = &Yt[((size_t)(bt * O_ + os) * KC + k) * NP + jb];
      *(uint4*)&yrow[q * 8]      = *(const uint4*)&sm.s2.ot[os][q * 8];
      *(uint4*)&yrow[32 + q * 8] = *(const uint4*)&sm.s2.ot[os][32 + q * 8];
    }
  }
}

// ---------------------------------------------------------------------------
// Stage 3: per-b GEMM  C[i,c] = sum_{K'} ASt[b][i][K'] * Yt[b][c][K'].
// 128x96 block tile -> 1024 blocks = 4 blocks/CU (28 KB LDS, 4 resident).
// 4 waves x (64x48), 16x16x32 bf16 MFMA, BK=64, global_load_lds width-16,
// XOR chunk swizzle (0 bank conflicts), XCD-aware block swizzle.
// ---------------------------------------------------------------------------
__global__ __launch_bounds__(256, 4) void k_gemm(
    const unsigned short* __restrict__ ASt, const unsigned short* __restrict__ Yt,
    float* __restrict__ out) {
  __shared__ unsigned short Al[128 * 64];   // 16 KB
  __shared__ unsigned short Bl[96 * 64];    // 12 KB
  const int tid = threadIdx.x;
  // block swizzle: bid%8 -> XCD; 2 b's per XCD for L2 locality
  const int bid = blockIdx.x;
  const int xcd = bid & 7, s = bid >> 3;          // s = 0..127
  const int b = xcd * 2 + (s >> 6);
  const int r = s & 63;
  const int ib = (r >> 3) * 128, cb = (r & 7) * 96;

  const unsigned short* Abase = ASt + ((size_t)b * NP + ib) * KP;
  const unsigned short* Bbase = Yt + ((size_t)b * CC + cb) * KP;
  const int w = tid >> 6, l = tid & 63, quad = l >> 4, lr = l & 15;
  const int wr = w & 1, wc = w >> 1;
  const int lrow = l >> 3, lchunk = l & 7;
  const int src_chunk = lchunk ^ lrow;            // XOR swizzle (staging side)
  const int p0 = quad ^ (lr & 7);                 // phys chunk, ks=0 (read side)

  f32x4 acc[4][3];
#pragma unroll
  for (int mi = 0; mi < 4; ++mi)
#pragma unroll
    for (int ci = 0; ci < 3; ++ci)
      acc[mi][ci] = (f32x4){0.f, 0.f, 0.f, 0.f};

  for (int kt = 0; kt < KP / 64; ++kt) {
    __syncthreads();                        // all waves done reading LDS(kt-1)
    const int k0 = kt * 64;
#pragma unroll
    for (int s4 = 0; s4 < 4; ++s4) {        // A: 128 rows
      const int row = w * 32 + s4 * 8;
      gl_lds16(Abase + (size_t)(row + lrow) * KP + k0 + src_chunk * 8,
               &Al[row * 64]);
    }
#pragma unroll
    for (int s4 = 0; s4 < 3; ++s4) {        // B: 96 rows
      const int row = w * 24 + s4 * 8;
      gl_lds16(Bbase + (size_t)(row + lrow) * KP + k0 + src_chunk * 8,
               &Bl[row * 64]);
    }
    __syncthreads();                        // vmcnt(0): LDS valid
#pragma unroll
    for (int ks = 0; ks < 2; ++ks) {
      const int pc = (p0 ^ (ks * 4)) * 8;   // swizzled chunk -> ushort offset
      bf16x8 a[4], bb[3];
#pragma unroll
      for (int mi = 0; mi < 4; ++mi)
        a[mi] = *(const bf16x8*)&Al[(wr * 64 + mi * 16 + lr) * 64 + pc];
#pragma unroll
      for (int ci = 0; ci < 3; ++ci)
        bb[ci] = *(const bf16x8*)&Bl[(wc * 48 + ci * 16 + lr) * 64 + pc];
#pragma unroll
      for (int mi = 0; mi < 4; ++mi)
#pragma unroll
        for (int ci = 0; ci < 3; ++ci)
          acc[mi][ci] = __builtin_amdgcn_mfma_f32_16x16x32_bf16(
              a[mi], bb[ci], acc[mi][ci], 0, 0, 0);
    }
  }

  // epilogue: C/D layout col=lane&15 (->c), row=quad*4+reg (->i). ReLU fused.
#pragma unroll
  for (int mi = 0; mi < 4; ++mi) {
    const int i = ib + wr * 64 + mi * 16 + quad * 4;
#pragma unroll
    for (int ci = 0; ci < 3; ++ci) {
      const int c = cb + wc * 48 + ci * 16 + lr;
      const int t = c >> 6, o = c & 63;      // 16-aligned segment: single t
#pragma unroll
      for (int r2 = 0; r2 < 4; ++r2) {
        if (i + r2 < N_) {
          const float v = acc[mi][ci][r2];
          out[((size_t)(b * T_ + t) * N_ + (i + r2)) * O_ + o] = v > 0.f ? v : 0.f;
        }
      }
    }
  }
}

// ---------------------------------------------------------------------------
extern "C" void kernel_launch(void* const* d_in, const int* in_sizes, int n_in,
                              void* d_out, int out_size, void* d_ws, size_t ws_size,
                              hipStream_t stream) {
  const float* x     = (const float*)d_in[0];
  const float* SAtt  = (const float*)d_in[1];
  const float* cheb  = (const float*)d_in[2];
  const float* Theta = (const float*)d_in[3];
  float* out = (float*)d_out;

  unsigned short* ASt = (unsigned short*)d_ws;                 // 100.7 MB
  unsigned short* Yt  = ASt + (size_t)B_ * NP * KC * NP;       //  75.5 MB

  k_prep<<<4096 + 3072, 256, 0, stream>>>(x, SAtt, cheb, Theta, ASt, Yt);
  k_gemm<<<1024, 256, 0, stream>>>(ASt, Yt, out);
}

// Round 5
// 326.631 us; speedup vs baseline: 1.1923x; 1.0487x over previous
//
#include <hip/hip_runtime.h>

// Problem constants
#define B_  16
#define T_  12
#define N_  1000
#define F_  64
#define KC  3
#define O_  64
#define NP  1024            // padded N (both i and j dims)
#define KP  (KC * NP)       // 3072 combined contraction length per b
#define CC  (T_ * O_)       // 768 output columns per b

typedef __bf16 bf16x8 __attribute__((ext_vector_type(8)));
typedef float  f32x4  __attribute__((ext_vector_type(4)));
typedef float  f32x16 __attribute__((ext_vector_type(16)));

__device__ __forceinline__ unsigned short f2bf(float f) {
  __bf16 h = (__bf16)f;                      // RNE convert
  return __builtin_bit_cast(unsigned short, h);
}

// async global->LDS, 16B per lane. LDS dest = wave-uniform base + lane*16.
__device__ __forceinline__ void gl_lds16(const void* g, void* l) {
  __builtin_amdgcn_global_load_lds(
      (const __attribute__((address_space(1))) unsigned int*)g,
      (__attribute__((address_space(3))) unsigned int*)l,
      16, 0, 0);
}

// ---------------------------------------------------------------------------
// Prep (fused stage1 + stage2, one launch):
//  blocks [0,4096):  ASt[b][ip][k][jp] = bf16(cheb[k,j,i]*SAtt[b,j,i]) (0-pad)
//  blocks [4096,7168): Yt[b][t][o][k][jp] = bf16(sum_f x[b,t,j,f]*Theta[k,f,o])
// ---------------------------------------------------------------------------
__global__ __launch_bounds__(256) void k_prep(
    const float* __restrict__ x, const float* __restrict__ SAtt,
    const float* __restrict__ cheb, const float* __restrict__ Theta,
    unsigned short* __restrict__ ASt, unsigned short* __restrict__ Yt) {
  __shared__ union {
    struct { unsigned short prod[KC][64][66]; } s1;                 // 25.9 KB
    struct {
      unsigned short thl[KC][64][72];   // Theta^T [k][o][f]
      unsigned short xl[64][72];        // x tile [j][f]
      unsigned short ot[64][72];        // out tile [o][j]
    } s2;                                                            // 45 KB
  } sm;
  const int tid = threadIdx.x;
  const int bid = blockIdx.x;

  if (bid < 4096) {
    // ---- stage 1: 64x64 (j x i) transpose tile -------------------------
    const int ib = (bid & 15) * 64, jb = ((bid >> 4) & 15) * 64, b = bid >> 8;
    const int ii4 = (tid & 15) * 4, jr = tid >> 4;
#pragma unroll
    for (int p = 0; p < 4; ++p) {
      const int jj = p * 16 + jr;
      const int gj = jb + jj;
      const int gjc = gj < N_ ? gj : N_ - 1;
      const int gi = ib + ii4;                  // N_%4==0: f4 never straddles
      const bool iok = gi < N_;
      const bool ok = iok && (gj < N_);
      float4 s4 = make_float4(0.f, 0.f, 0.f, 0.f);
      if (iok) s4 = *(const float4*)&SAtt[((size_t)b * N_ + gjc) * N_ + gi];
#pragma unroll
      for (int k = 0; k < KC; ++k) {
        float4 c4 = make_float4(0.f, 0.f, 0.f, 0.f);
        if (iok) c4 = *(const float4*)&cheb[((size_t)k * N_ + gjc) * N_ + gi];
        ushort2 lo, hi;
        lo.x = ok ? f2bf(c4.x * s4.x) : (unsigned short)0;
        lo.y = ok ? f2bf(c4.y * s4.y) : (unsigned short)0;
        hi.x = ok ? f2bf(c4.z * s4.z) : (unsigned short)0;
        hi.y = ok ? f2bf(c4.w * s4.w) : (unsigned short)0;
        *(ushort2*)&sm.s1.prod[k][jj][ii4]     = lo;
        *(ushort2*)&sm.s1.prod[k][jj][ii4 + 2] = hi;
      }
    }
    __syncthreads();
    const int j8 = (tid & 7) * 8, i0 = tid >> 3;
#pragma unroll
    for (int p = 0; p < 2; ++p) {
      const int iw = p * 32 + i0;
#pragma unroll
      for (int k = 0; k < KC; ++k) {
        unsigned short v[8];
#pragma unroll
        for (int m = 0; m < 8; ++m) v[m] = sm.s1.prod[k][j8 + m][iw];
        *(uint4*)&ASt[((size_t)(b * NP + ib + iw) * KC + k) * NP + jb + j8] =
            *(uint4*)v;
      }
    }
  } else {
    // ---- stage 2: MFMA A=Theta^T (M=o=64), B=x strip, K=f=64 ----------
    const int b2 = bid - 4096;
    const int jb = (b2 & 15) * 64, bt = b2 >> 4;   // bt = b*T + t
#pragma unroll
    for (int it = 0; it < 12; ++it) {
      const int e = (tid + it * 256) * 4;
      const int k = e >> 12, f = (e >> 6) & 63, o0 = e & 63;
      const float4 v = *(const float4*)&Theta[e];
      sm.s2.thl[k][o0 + 0][f] = f2bf(v.x);
      sm.s2.thl[k][o0 + 1][f] = f2bf(v.y);
      sm.s2.thl[k][o0 + 2][f] = f2bf(v.z);
      sm.s2.thl[k][o0 + 3][f] = f2bf(v.w);
    }
    const float* xrow = x + ((size_t)bt * N_ + jb) * F_;
#pragma unroll
    for (int p = 0; p < 4; ++p) {
      const int i4 = tid + p * 256;            // float4 index, 0..1023
      const int fl = i4 * 4, j = fl >> 6, f = fl & 63;
      float4 v;
      if (jb + j < N_) v = ((const float4*)xrow)[i4];
      else             v = make_float4(0.f, 0.f, 0.f, 0.f);
      ushort4 u;
      u.x = f2bf(v.x); u.y = f2bf(v.y); u.z = f2bf(v.z); u.w = f2bf(v.w);
      *(ushort4*)&sm.s2.xl[j][f] = u;
    }
    __syncthreads();

    const int w = tid >> 6, l = tid & 63, quad = l >> 4, lr = l & 15;
    const int os = tid >> 2, q = tid & 3;
#pragma unroll
    for (int k = 0; k < KC; ++k) {
      f32x4 acc[4];
#pragma unroll
      for (int mi = 0; mi < 4; ++mi) acc[mi] = (f32x4){0.f, 0.f, 0.f, 0.f};
#pragma unroll
      for (int ks = 0; ks < 2; ++ks) {
        const int fo = ks * 32 + quad * 8;
        const bf16x8 bb = *(const bf16x8*)&sm.s2.xl[w * 16 + lr][fo];
#pragma unroll
        for (int mi = 0; mi < 4; ++mi) {
          const bf16x8 a = *(const bf16x8*)&sm.s2.thl[k][mi * 16 + lr][fo];
          acc[mi] =
              __builtin_amdgcn_mfma_f32_16x16x32_bf16(a, bb, acc[mi], 0, 0, 0);
        }
      }
      __syncthreads();                          // protect ot from prior readers
#pragma unroll
      for (int mi = 0; mi < 4; ++mi)
#pragma unroll
        for (int r = 0; r < 4; ++r)
          sm.s2.ot[mi * 16 + quad * 4 + r][w * 16 + lr] = f2bf(acc[mi][r]);
      __syncthreads();
      unsigned short* yrow = &Yt[((size_t)(bt * O_ + os) * KC + k) * NP + jb];
      *(uint4*)&yrow[q * 8]      = *(const uint4*)&sm.s2.ot[os][q * 8];
      *(uint4*)&yrow[32 + q * 8] = *(const uint4*)&sm.s2.ot[os][32 + q * 8];
    }
  }
}

// ---------------------------------------------------------------------------
// Stage 3: per-b GEMM  C[i,c] = sum_{K'} ASt[b][i][K'] * Yt[b][c][K'].
// R2 structure: 128x128 block tile, BK=64, both operands via global_load_lds
// (width 16) with XOR chunk swizzle (0 conflicts), 768 blocks = 3/CU.
// CHANGE: 32x32x16 MFMA (2x2 per wave) -- same frag bytes, half the MFMA
// instruction count, higher-ceiling pipe. XCD-aware block swizzle.
// ---------------------------------------------------------------------------
__global__ __launch_bounds__(256, 2) void k_gemm(
    const unsigned short* __restrict__ ASt, const unsigned short* __restrict__ Yt,
    float* __restrict__ out) {
  __shared__ unsigned short Al[128 * 64];   // 16 KB
  __shared__ unsigned short Bl[128 * 64];   // 16 KB
  const int tid = threadIdx.x;
  // block swizzle: bid%8 -> XCD; 2 b's per XCD for L2 locality
  const int bid = blockIdx.x;
  const int xcd = bid & 7, s = bid >> 3;          // s = 0..95
  const int b = xcd * 2 + (s / 48);
  const int r48 = s % 48;
  const int ib = (r48 / 6) * 128, cb = (r48 % 6) * 128;

  const unsigned short* Abase = ASt + ((size_t)b * NP + ib) * KP;
  const unsigned short* Bbase = Yt + ((size_t)b * CC + cb) * KP;
  const int w = tid >> 6, l = tid & 63;
  const int l32 = l & 31, lh = l >> 5;            // 32x32 operand indices
  const int wr = w & 1, wc = w >> 1;
  const int lrow = l >> 3, lchunk = l & 7;
  const int src_chunk = lchunk ^ lrow;            // XOR swizzle (staging side)

  f32x16 acc[2][2];
#pragma unroll
  for (int mi = 0; mi < 2; ++mi)
#pragma unroll
    for (int ci = 0; ci < 2; ++ci)
      acc[mi][ci] = (f32x16){0.f};

  // fragment row/chunk bases (row&7 == l32&7 for all our rows)
  const int swz = l32 & 7;

  for (int kt = 0; kt < KP / 64; ++kt) {
    __syncthreads();                        // all waves done reading LDS(kt-1)
    const int k0 = kt * 64;
#pragma unroll
    for (int s4 = 0; s4 < 4; ++s4) {        // A: 128 rows, wave-uniform base
      const int row = w * 32 + s4 * 8;
      gl_lds16(Abase + (size_t)(row + lrow) * KP + k0 + src_chunk * 8,
               &Al[row * 64]);
    }
#pragma unroll
    for (int s4 = 0; s4 < 4; ++s4) {        // B: 128 rows
      const int row = w * 32 + s4 * 8;
      gl_lds16(Bbase + (size_t)(row + lrow) * KP + k0 + src_chunk * 8,
               &Bl[row * 64]);
    }
    __syncthreads();                        // vmcnt(0): LDS valid
#pragma unroll
    for (int ks = 0; ks < 4; ++ks) {        // 4 k-steps of K=16
      const int chunk = ks * 2 + lh;        // logical 16B chunk index
      const int pc = (chunk ^ swz) * 8;     // swizzled -> ushort offset
      bf16x8 a[2], bb[2];
#pragma unroll
      for (int mi = 0; mi < 2; ++mi)
        a[mi] = *(const bf16x8*)&Al[(wr * 64 + mi * 32 + l32) * 64 + pc];
#pragma unroll
      for (int ci = 0; ci < 2; ++ci)
        bb[ci] = *(const bf16x8*)&Bl[(wc * 64 + ci * 32 + l32) * 64 + pc];
#pragma unroll
      for (int mi = 0; mi < 2; ++mi)
#pragma unroll
        for (int ci = 0; ci < 2; ++ci)
          acc[mi][ci] = __builtin_amdgcn_mfma_f32_32x32x16_bf16(
              a[mi], bb[ci], acc[mi][ci], 0, 0, 0);
    }
  }

  // epilogue: 32x32 C/D layout col=lane&31 (->c), row=(reg&3)+8*(reg>>2)+
  // 4*(lane>>5) (->i)  [m74/m101 verified]. ReLU fused.
#pragma unroll
  for (int mi = 0; mi < 2; ++mi) {
#pragma unroll
    for (int ci = 0; ci < 2; ++ci) {
      const int c = cb + wc * 64 + ci * 32 + l32;
      const int t = c >> 6, o = c & 63;      // 32-aligned segment: single t
      float* orow = out + ((size_t)(b * T_ + t) * N_) * O_ + o;
#pragma unroll
      for (int r = 0; r < 16; ++r) {
        const int i = ib + wr * 64 + mi * 32 + (r & 3) + 8 * (r >> 2) + 4 * lh;
        if (i < N_) {
          const float v = acc[mi][ci][r];
          orow[(size_t)i * O_] = v > 0.f ? v : 0.f;
        }
      }
    }
  }
}

// ---------------------------------------------------------------------------
extern "C" void kernel_launch(void* const* d_in, const int* in_sizes, int n_in,
                              void* d_out, int out_size, void* d_ws, size_t ws_size,
                              hipStream_t stream) {
  const float* x     = (const float*)d_in[0];
  const float* SAtt  = (const float*)d_in[1];
  const float* cheb  = (const float*)d_in[2];
  const float* Theta = (const float*)d_in[3];
  float* out = (float*)d_out;

  unsigned short* ASt = (unsigned short*)d_ws;                 // 100.7 MB
  unsigned short* Yt  = ASt + (size_t)B_ * NP * KC * NP;       //  75.5 MB

  k_prep<<<4096 + 3072, 256, 0, stream>>>(x, SAtt, cheb, Theta, ASt, Yt);
  k_gemm<<<768, 256, 0, stream>>>(ASt, Yt, out);
}